// Round 5
// baseline (102.018 us; speedup 1.0000x reference)
//
#include <hip/hip_runtime.h>

typedef __bf16 bf16_t;
typedef bf16_t bf16x4 __attribute__((ext_vector_type(4)));
typedef bf16_t bf16x8 __attribute__((ext_vector_type(8)));
typedef float f32x4 __attribute__((ext_vector_type(4)));
typedef float f32x16 __attribute__((ext_vector_type(16)));

namespace {
constexpr int kNH  = 16;
constexpr int kHD  = 64;
constexpr int kHID = kNH * kHD;   // 1024
constexpr int kSQ  = 2048;
constexpr int kKP  = 72;          // Q LDS pitch (bf16)
constexpr int kOmPitch = 68;      // epilogue float pitch
// LDS: Q stage 64*72*2 = 9216 B, then epilogue region (disjoint -> no race):
// 12 waves * 32 rows * 68 * 4 = 104448 B + larr 12*64*4 = 3072 B
constexpr int kQBytes  = 9216;
constexpr int kSmBytes = kQBytes + 12 * 32 * kOmPitch * 4 + 12 * 64 * 4; // 116736
constexpr int kKbElems = kNH * kSQ * kHD;  // 2,097,152 bf16 = 4 MB
}

// ---------------------------------------------------------------------------
// Prep pass (unchanged): head-major bf16 K pack + kappa-order V gather.
// Kb[head][t][d]: a 16B load at (t*64 + 16*tt + 8*h) IS a QK^T A-fragment.
// Vb: pre-gathered so a 64B/lane load IS the PV A-fragment set.
// ---------------------------------------------------------------------------
__global__ __launch_bounds__(256)
void prep_kernel(const float* __restrict__ Kg, const float* __restrict__ Vg,
                 bf16_t* __restrict__ Kb, bf16_t* __restrict__ Vb) {
  const int bid = blockIdx.x;
  const int tid = threadIdx.x;
  if (bid < 1024) {
    const int o    = (bid * 256 + tid) * 8;    // bf16 out index in Kb
    const int head = o >> 17;                  // 131072 = 2048*64
    const int t    = (o >> 6) & 2047;
    const int d0   = o & 63;
    const float4 f0 = *(const float4*)(Kg + (size_t)t * kHID + head * kHD + d0);
    const float4 f1 = *(const float4*)(Kg + (size_t)t * kHID + head * kHD + d0 + 4);
    bf16x8 hk;
    hk[0] = (bf16_t)f0.x; hk[1] = (bf16_t)f0.y; hk[2] = (bf16_t)f0.z; hk[3] = (bf16_t)f0.w;
    hk[4] = (bf16_t)f1.x; hk[5] = (bf16_t)f1.y; hk[6] = (bf16_t)f1.z; hk[7] = (bf16_t)f1.w;
    *(bf16x8*)(Kb + o) = hk;
  } else {
    const int vb   = bid - 1024;               // one (head, tile) per block
    const int head = vb >> 6;
    const int tile = vb & 63;
    const int lane = tid >> 2;                 // 0..63
    const int hh   = lane >> 5;
    const int m31  = lane & 31;
    const int q    = tid & 3;
    const int db   = q >> 1, tp = q & 1;
    const int tb   = tile * 32 + 4 * hh + 16 * tp;
    const int d    = m31 + 32 * db;
    const float* src = Vg + (size_t)tb * kHID + head * kHD + d;
    bf16x8 hv;
    #pragma unroll
    for (int j = 0; j < 8; ++j)
      hv[j] = (bf16_t)src[(size_t)((j & 3) + 8 * (j >> 2)) * kHID];
    *(bf16x8*)(Vb + ((size_t)(head * 64 + tile) * 64 + lane) * 32 + (db * 16 + tp * 8)) = hv;
  }
}

// R15: occupancy 2 -> 3 waves/SIMD. Four rounds of evidence: fattn pinned at
// ~40us through byte-halving, balance, and zero-LDS rewrites; per-SIMD math
// says ~5800 cy/iteration-slot vs ~470 cy issue work (8% issue efficiency) at
// 2 waves/SIMD. Fix: split q-halves across waves — 12 waves/block (2 halves x
// 6 key-groups), 768 threads, launch_bounds(768,3) -> 170-reg cap, per-wave
// state ~150 (Q16 K32 V32 c16 Oa32[AGPR] + misc). Also: branchless clamped
// prefetch (static vmcnt), no diagonal-skip branch (waves above diagonal just
// iterate less), setprio around MFMA clusters.
__global__ __launch_bounds__(768, 3)
void fattn_kernel(const float* __restrict__ Qg, const bf16_t* __restrict__ Kb,
                  const bf16_t* __restrict__ Vb, float* __restrict__ Og) {
  __shared__ __align__(16) unsigned char smraw[kSmBytes];
  bf16_t* qs = (bf16_t*)smraw;         // Q tile 64 x kKP

  const int bid  = blockIdx.x;
  const int head = bid & (kNH - 1);
  const int ip   = bid >> 4;          // 0..15: pair (31-ip, ip)

  const int tid  = threadIdx.x;
  const int wave = tid >> 6;          // 0..11
  const int lane = tid & 63;
  const int h    = lane >> 5;
  const int m31  = lane & 31;
  const int hw   = wave / 6;          // q-half owned by this wave (0 or 1)
  const int kg   = wave - 6 * hw;     // key-group: tiles jt == kg (mod 6)

  const float kQScale = 0.125f * 1.44269504088896340736f;  // 1/sqrt(64)*log2(e)

  // per-lane fragment base pointers into the packed bf16 buffers
  const bf16_t* kfb = Kb + (size_t)head * (kSQ * kHD) + (size_t)m31 * kHD + 8 * h;
  const bf16_t* vfb = Vb + ((size_t)head * 64 * 64 + lane) * 32;

  // epilogue LDS regions (disjoint from qs -> no extra barrier needed)
  float* fv   = (float*)(smraw + kQBytes);
  float* Om   = fv + wave * 32 * kOmPitch;     // per-wave 32 rows x 68
  float* larr = fv + 12 * 32 * kOmPitch;       // 12 waves x 64 l-partials

  for (int halfq = 0; halfq < 2; ++halfq) {
    const int mblk = halfq ? ip : (31 - ip);   // big q-tile first
    const int m0   = mblk * 64;
    const int q0   = m0 + 32 * hw;             // this wave's 32 q-rows
    const int jtmax = 2 * mblk + hw;           // last key tile for this wave

    // ---- stage Q tile (64 rows); first barrier covers prior merge reads ----
    __syncthreads();
    #pragma unroll
    for (int i = 0; i < 2; ++i) {
      const int idx = tid + 768 * i;          // 1024 float4s
      if (idx < 1024) {
        const int row = idx >> 4;
        const int c4  = (idx & 15) * 4;
        const float4 f = *(const float4*)(Qg + (size_t)(m0 + row) * kHID + head * kHD + c4);
        bf16x4 qv;
        qv[0] = (bf16_t)(f.x * kQScale); qv[1] = (bf16_t)(f.y * kQScale);
        qv[2] = (bf16_t)(f.z * kQScale); qv[3] = (bf16_t)(f.w * kQScale);
        *(bf16x4*)(qs + row * kKP + c4) = qv;
      }
    }
    __syncthreads();

    // ---- hoist this wave's Q fragments: 4 x bf16x8 = 16 VGPRs ----
    const bf16_t* qrow = qs + (32 * hw + m31) * kKP + 8 * h;
    bf16x8 qf0 = *(const bf16x8*)(qrow +  0);
    bf16x8 qf1 = *(const bf16x8*)(qrow + 16);
    bf16x8 qf2 = *(const bf16x8*)(qrow + 32);
    bf16x8 qf3 = *(const bf16x8*)(qrow + 48);

    // O^T accumulators (d 0..31 / 32..63); l partial
    f32x16 Oa0, Oa1;
    #pragma unroll
    for (int r = 0; r < 16; ++r) { Oa0[r] = 0.f; Oa1[r] = 0.f; }
    float lacc = 0.f;

    // ---- prologue prefetch (tile kg always a valid address) ----
    bf16x8 k0, k1, k2, k3, v0, v1, v2, v3;
    {
      const bf16_t* kp = kfb + (size_t)kg * 2048;
      k0 = *(const bf16x8*)(kp);      k1 = *(const bf16x8*)(kp + 16);
      k2 = *(const bf16x8*)(kp + 32); k3 = *(const bf16x8*)(kp + 48);
      const bf16_t* vp = vfb + (size_t)kg * 2048;
      v0 = *(const bf16x8*)(vp);      v1 = *(const bf16x8*)(vp + 8);
      v2 = *(const bf16x8*)(vp + 16); v3 = *(const bf16x8*)(vp + 24);
    }

    for (int jt = kg; jt <= jtmax; jt += 6) {
      const int kv0 = jt * 32;
      // clamped next tile index: branchless -> static vmcnt at uses
      const int jn = (jt + 6 <= jtmax) ? (jt + 6) : kg;

      // --- QK^T (K frags die here) ---
      f32x16 c;
      #pragma unroll
      for (int r = 0; r < 16; ++r) c[r] = 0.f;
      __builtin_amdgcn_s_setprio(1);
      c = __builtin_amdgcn_mfma_f32_32x32x16_bf16(k0, qf0, c, 0, 0, 0);
      c = __builtin_amdgcn_mfma_f32_32x32x16_bf16(k1, qf1, c, 0, 0, 0);
      c = __builtin_amdgcn_mfma_f32_32x32x16_bf16(k2, qf2, c, 0, 0, 0);
      c = __builtin_amdgcn_mfma_f32_32x32x16_bf16(k3, qf3, c, 0, 0, 0);
      __builtin_amdgcn_s_setprio(0);

      // --- prefetch next K into the same regs (covers softmax+PV) ---
      {
        const bf16_t* kp = kfb + (size_t)jn * 2048;
        k0 = *(const bf16x8*)(kp);      k1 = *(const bf16x8*)(kp + 16);
        k2 = *(const bf16x8*)(kp + 32); k3 = *(const bf16x8*)(kp + 48);
      }

      // --- softmax ---
      float p[16];
      if (kv0 == q0) {   // diagonal subtile
        #pragma unroll
        for (int r = 0; r < 16; ++r) {
          const int kr = (r & 3) + 8 * (r >> 2) + 4 * h;
          const float e = __builtin_amdgcn_exp2f(c[r]);
          p[r] = (kr <= m31) ? e : 0.f;
          lacc += p[r];
        }
      } else {
        #pragma unroll
        for (int r = 0; r < 16; ++r) { p[r] = __builtin_amdgcn_exp2f(c[r]); lacc += p[r]; }
      }
      bf16x8 pb0, pb1;
      #pragma unroll
      for (int j = 0; j < 8; ++j) { pb0[j] = (bf16_t)p[j]; pb1[j] = (bf16_t)p[8 + j]; }

      // --- PV (V frags die here) ---
      __builtin_amdgcn_s_setprio(1);
      Oa0 = __builtin_amdgcn_mfma_f32_32x32x16_bf16(v0, pb0, Oa0, 0, 0, 0);
      Oa1 = __builtin_amdgcn_mfma_f32_32x32x16_bf16(v2, pb0, Oa1, 0, 0, 0);
      Oa0 = __builtin_amdgcn_mfma_f32_32x32x16_bf16(v1, pb1, Oa0, 0, 0, 0);
      Oa1 = __builtin_amdgcn_mfma_f32_32x32x16_bf16(v3, pb1, Oa1, 0, 0, 0);
      __builtin_amdgcn_s_setprio(0);

      // --- prefetch next V into the same regs (covers next QK^T) ---
      {
        const bf16_t* vp = vfb + (size_t)jn * 2048;
        v0 = *(const bf16x8*)(vp);      v1 = *(const bf16x8*)(vp + 8);
        v2 = *(const bf16x8*)(vp + 16); v3 = *(const bf16x8*)(vp + 24);
      }
    }

    // ---- epilogue: single pass, 6-way additive merge per q-half via LDS ----
    #pragma unroll
    for (int q = 0; q < 4; ++q) {
      f32x4 w0, w1;
      #pragma unroll
      for (int e = 0; e < 4; ++e) { w0[e] = Oa0[4 * q + e]; w1[e] = Oa1[4 * q + e]; }
      *(f32x4*)(Om + (size_t)m31 * kOmPitch + 8 * q + 4 * h)      = w0;
      *(f32x4*)(Om + (size_t)m31 * kOmPitch + 32 + 8 * q + 4 * h) = w1;
    }
    larr[wave * 64 + lane] = lacc;
    __syncthreads();
    #pragma unroll
    for (int i = 0; i < 2; ++i) {
      const int idx = tid + 768 * i;          // 1024 items: 64 rows x 16 col4s
      if (idx < 1024) {
        const int row = idx >> 4;
        const int c4  = (idx & 15) * 4;
        const int r32 = row & 31;
        const int wb  = (row >> 5) * 6;       // 6 waves of this q-half
        float l = 0.f;
        #pragma unroll
        for (int w = 0; w < 6; ++w)
          l += larr[(wb + w) * 64 + r32] + larr[(wb + w) * 64 + 32 + r32];
        const float inv = 1.f / l;
        f32x4 o;
        #pragma unroll
        for (int e = 0; e < 4; ++e) o[e] = 0.f;
        #pragma unroll
        for (int w = 0; w < 6; ++w) {
          const f32x4 a = *(const f32x4*)(fv + (size_t)(wb + w) * 32 * kOmPitch
                                             + (size_t)r32 * kOmPitch + c4);
          #pragma unroll
          for (int e = 0; e < 4; ++e) o[e] += a[e];
        }
        #pragma unroll
        for (int e = 0; e < 4; ++e) o[e] *= inv;
        *(f32x4*)(Og + (size_t)(m0 + row) * kHID + head * kHD + c4) = o;
      }
    }
  }
}

extern "C" void kernel_launch(void* const* d_in, const int* in_sizes, int n_in,
                              void* d_out, int out_size, void* d_ws, size_t ws_size,
                              hipStream_t stream) {
  (void)in_sizes; (void)n_in; (void)ws_size; (void)out_size;
  const float* Q = (const float*)d_in[0];
  const float* K = (const float*)d_in[1];
  const float* V = (const float*)d_in[2];
  float* O = (float*)d_out;
  bf16_t* Kb = (bf16_t*)d_ws;            // 4 MB: [head][t][d] bf16
  bf16_t* Vb = Kb + kKbElems;            // 4 MB: pre-gathered kappa order
  hipLaunchKernelGGL(prep_kernel, dim3(2048), dim3(256), 0, stream, K, V, Kb, Vb);
  dim3 grid(256);    // 16 heads x 16 q-tile PAIRS (31-ip, ip)
  dim3 block(768);   // 12 waves = 2 q-halves x 6 key-groups, 3 waves/SIMD
  hipLaunchKernelGGL(fattn_kernel, grid, block, 0, stream, Q, Kb, Vb, O);
}